// Round 1
// baseline (936.260 us; speedup 1.0000x reference)
//
#include <hip/hip_runtime.h>
#include <hip/hip_bf16.h>
#include <cmath>

#define B_ 2
#define H_ 8
#define S_ 2048
#define D_ 64
#define TQ 16
#define TK 32
#define NKT (S_ / TK)

typedef __bf16 bf16x8 __attribute__((ext_vector_type(8)));
typedef float  f32x4  __attribute__((ext_vector_type(4)));

#define VT_STRIDE 40   // padded key stride for V^T tile (keeps 16B align, spreads banks)
#define S_STRIDE  32
#define A_STRIDE  32

// LDS budget: vT 8*64*40*2 = 40960 ; sbuf 8*16*32*4 = 16384 ; abuf 8*16*32*2 = 8192
// total = 65536 B

__global__ __launch_bounds__(256, 1)
void attn_fused(const float* __restrict__ qg, const float* __restrict__ kg,
                const float* __restrict__ vg, const int* __restrict__ maskg,
                float* __restrict__ zout, float* __restrict__ attout)
{
    __shared__ __bf16 vT[H_][D_][VT_STRIDE];
    __shared__ float  sbuf[H_][TQ][S_STRIDE];
    __shared__ __bf16 abuf[H_][TQ][A_STRIDE];

    const int tid  = threadIdx.x;
    const int lane = tid & 63;
    const int wave = tid >> 6;      // 0..3 ; wave handles heads 2w, 2w+1
    const int n16  = lane & 15;
    const int quad = lane >> 4;

    const int b  = blockIdx.x >> 7;          // 2 batches
    const int q0 = (blockIdx.x & 127) * TQ;  // 128 q-tiles

    const float scale = 0.35355339059327373f;  // 1/sqrt(H=8) -- k.shape[1] trap!

    // ---- Q fragments, hi/lo split-bf16, held in registers for the whole kernel ----
    bf16x8 qhi[2][2], qlo[2][2];
    #pragma unroll
    for (int hh = 0; hh < 2; ++hh) {
        const int h = wave * 2 + hh;
        const float* qp = qg + (size_t)((b * H_ + h) * S_ + q0 + n16) * D_;
        #pragma unroll
        for (int kk = 0; kk < 2; ++kk) {
            const float4* p = (const float4*)(qp + kk * 32 + quad * 8);
            float4 f0 = p[0], f1 = p[1];
            float fv[8] = {f0.x, f0.y, f0.z, f0.w, f1.x, f1.y, f1.z, f1.w};
            bf16x8 hi, lo;
            #pragma unroll
            for (int j = 0; j < 8; ++j) {
                float fs = fv[j] * scale;
                __bf16 h16 = (__bf16)fs;
                hi[j] = h16;
                lo[j] = (__bf16)(fs - (float)h16);
            }
            qhi[hh][kk] = hi; qlo[hh][kk] = lo;
        }
    }

    f32x4 acc[2][4];
    #pragma unroll
    for (int hh = 0; hh < 2; ++hh)
        #pragma unroll
        for (int d = 0; d < 4; ++d)
            acc[hh][d] = (f32x4){0.f, 0.f, 0.f, 0.f};

    for (int kt = 0; kt < NKT; ++kt) {
        const int k0 = kt * TK;

        // ---- stage V^T tile into LDS (bf16): wave w stages keys w*8..w*8+7, lane = d ----
        #pragma unroll
        for (int h = 0; h < H_; ++h) {
            const float* vp = vg + (size_t)((b * H_ + h) * S_ + k0 + wave * 8) * D_ + lane;
            bf16x8 pk;
            #pragma unroll
            for (int j = 0; j < 8; ++j)
                pk[j] = (__bf16)vp[(size_t)j * D_];   // coalesced: 64 lanes x 4B contiguous
            *(bf16x8*)&vT[h][lane][wave * 8] = pk;    // 16B store, key-contiguous
        }

        // ---- QK^T via split-bf16 MFMA: s = qhi*khi + qlo*khi + qhi*klo (fp32-grade) ----
        #pragma unroll
        for (int hh = 0; hh < 2; ++hh) {
            const int h = wave * 2 + hh;
            #pragma unroll
            for (int ks = 0; ks < 2; ++ks) {
                f32x4 c = (f32x4){0.f, 0.f, 0.f, 0.f};
                #pragma unroll
                for (int kk = 0; kk < 2; ++kk) {
                    // B-operand: lane holds K[k0+ks*16+n16][kk*32+quad*8+j], 8 contiguous d
                    const float* kp = kg + (size_t)((b * H_ + h) * S_ + k0 + ks * 16 + n16) * D_
                                      + kk * 32 + quad * 8;
                    float4 f0 = ((const float4*)kp)[0], f1 = ((const float4*)kp)[1];
                    float fv[8] = {f0.x, f0.y, f0.z, f0.w, f1.x, f1.y, f1.z, f1.w};
                    bf16x8 khi, klo;
                    #pragma unroll
                    for (int j = 0; j < 8; ++j) {
                        __bf16 h16 = (__bf16)fv[j];
                        khi[j] = h16;
                        klo[j] = (__bf16)(fv[j] - (float)h16);
                    }
                    c = __builtin_amdgcn_mfma_f32_16x16x32_bf16(qhi[hh][kk], khi, c, 0, 0, 0);
                    c = __builtin_amdgcn_mfma_f32_16x16x32_bf16(qlo[hh][kk], khi, c, 0, 0, 0);
                    c = __builtin_amdgcn_mfma_f32_16x16x32_bf16(qhi[hh][kk], klo, c, 0, 0, 0);
                }
                // C layout: row = quad*4+r (q), col = n16 (key within 16-tile)
                #pragma unroll
                for (int r = 0; r < 4; ++r)
                    sbuf[h][quad * 4 + r][ks * 16 + n16] = c[r];
            }
        }
        __syncthreads();

        // ---- softmax ACROSS HEADS (axis=1!) + mask; write att to global + LDS(bf16) ----
        #pragma unroll
        for (int rep = 0; rep < 2; ++rep) {
            const int pos = tid + rep * 256;       // 512 positions = 16q x 32k
            const int qq  = pos >> 5;
            const int kk2 = pos & 31;
            const int msk = maskg[(size_t)(b * S_ + q0 + qq) * S_ + k0 + kk2];
            float sv[8];
            float mx = -INFINITY;
            #pragma unroll
            for (int h = 0; h < H_; ++h) { sv[h] = sbuf[h][qq][kk2]; mx = fmaxf(mx, sv[h]); }
            float sum = 0.f;
            #pragma unroll
            for (int h = 0; h < H_; ++h) { sv[h] = __expf(sv[h] - mx); sum += sv[h]; }
            const float inv = 1.0f / sum;
            #pragma unroll
            for (int h = 0; h < H_; ++h) {
                // mask==0 => all heads tied at -1e11 => uniform softmax 1/8
                const float a = (msk == 0) ? 0.125f : sv[h] * inv;
                attout[(size_t)((b * H_ + h) * S_ + q0 + qq) * S_ + k0 + kk2] = a;
                abuf[h][qq][kk2] = (__bf16)a;
            }
        }
        __syncthreads();

        // ---- PV: A = att (M=16q, K=32 keys), B = V^T tile (K=32 keys, N=16 d) ----
        #pragma unroll
        for (int hh = 0; hh < 2; ++hh) {
            const int h = wave * 2 + hh;
            bf16x8 af = *(const bf16x8*)&abuf[h][n16][quad * 8];   // A[m=n16][k=quad*8+j]
            #pragma unroll
            for (int dsb = 0; dsb < 4; ++dsb) {
                bf16x8 bf = *(const bf16x8*)&vT[h][dsb * 16 + n16][quad * 8]; // B[k][n=d]
                acc[hh][dsb] = __builtin_amdgcn_mfma_f32_16x16x32_bf16(af, bf, acc[hh][dsb], 0, 0, 0);
            }
        }
        __syncthreads();   // protect vT/sbuf/abuf before next iteration overwrites
    }

    // ---- epilogue: z (C layout: row = quad*4+r -> q, col = n16 -> d within 16-tile) ----
    #pragma unroll
    for (int hh = 0; hh < 2; ++hh) {
        const int h = wave * 2 + hh;
        #pragma unroll
        for (int dsb = 0; dsb < 4; ++dsb)
            #pragma unroll
            for (int r = 0; r < 4; ++r)
                zout[(size_t)((b * H_ + h) * S_ + q0 + quad * 4 + r) * D_ + dsb * 16 + n16]
                    = acc[hh][dsb][r];
    }
}

extern "C" void kernel_launch(void* const* d_in, const int* in_sizes, int n_in,
                              void* d_out, int out_size, void* d_ws, size_t ws_size,
                              hipStream_t stream) {
    const float* q    = (const float*)d_in[0];
    const float* k    = (const float*)d_in[1];
    const float* v    = (const float*)d_in[2];
    const int*   mask = (const int*)d_in[3];
    float* z   = (float*)d_out;
    float* att = (float*)d_out + (size_t)B_ * H_ * S_ * D_;   // outputs concatenated: (z, att_score)
    attn_fused<<<dim3(B_ * (S_ / TQ)), dim3(256), 0, stream>>>(q, k, v, mask, z, att);
}

// Round 2
// 532.526 us; speedup vs baseline: 1.7581x; 1.7581x over previous
//
#include <hip/hip_runtime.h>
#include <hip/hip_bf16.h>
#include <cmath>

#define B_ 2
#define H_ 8
#define S_ 2048
#define D_ 64
#define TQ 16
#define TK 32
#define KCHUNKS 8
#define TPC ((S_ / TK) / KCHUNKS)   // 8 k-tiles of 32 per chunk

typedef __bf16 bf16x8 __attribute__((ext_vector_type(8)));
typedef float  f32x4  __attribute__((ext_vector_type(4)));

#define SB_STRIDE 33   // fp32 row stride: breaks 4-way bank conflict on s-store
#define AB_STRIDE 40   // bf16 row stride: 80 B rows keep 16 B-aligned A-frags

// LDS: sbuf 8*16*33*4 = 16896 B ; abuf 8*16*40*2 = 10240 B ; total 27136 B

__global__ __launch_bounds__(256, 4)
void attn_fused(const float* __restrict__ qg, const float* __restrict__ kg,
                const float* __restrict__ vg, const int* __restrict__ maskg,
                float* __restrict__ zout, float* __restrict__ attout)
{
    __shared__ float  sbuf[H_][TQ][SB_STRIDE];
    __shared__ __bf16 abuf[H_][TQ][AB_STRIDE];

    const int tid  = threadIdx.x;
    const int lane = tid & 63;
    const int wave = tid >> 6;      // 0..3 ; wave handles heads 2w, 2w+1
    const int n16  = lane & 15;
    const int quad = lane >> 4;

    // grid: 2048 blocks = chunk(8) x qt(128) x b(2); chunk slow so concurrent
    // blocks share one K/V chunk slice in L2
    const int bi    = blockIdx.x;
    const int b     = bi & 1;
    const int qt    = (bi >> 1) & 127;
    const int chunk = bi >> 8;
    const int q0    = qt * TQ;

    const float scale = 0.35355339059327373f;  // 1/sqrt(H=8) -- k.shape[1] trap!

    // ---- Q fragments, hi/lo split-bf16, in registers for the whole kernel ----
    bf16x8 qhi[2][2], qlo[2][2];
    #pragma unroll
    for (int hh = 0; hh < 2; ++hh) {
        const int h = wave * 2 + hh;
        const float* qp = qg + (size_t)((b * H_ + h) * S_ + q0 + n16) * D_;
        #pragma unroll
        for (int kk = 0; kk < 2; ++kk) {
            const float4* p = (const float4*)(qp + kk * 32 + quad * 8);
            float4 f0 = p[0], f1 = p[1];
            float fv[8] = {f0.x, f0.y, f0.z, f0.w, f1.x, f1.y, f1.z, f1.w};
            bf16x8 hi, lo;
            #pragma unroll
            for (int j = 0; j < 8; ++j) {
                float fs = fv[j] * scale;
                __bf16 h16 = (__bf16)fs;
                hi[j] = h16;
                lo[j] = (__bf16)(fs - (float)h16);
            }
            qhi[hh][kk] = hi; qlo[hh][kk] = lo;
        }
    }

    f32x4 acc[2][4];
    #pragma unroll
    for (int hh = 0; hh < 2; ++hh)
        #pragma unroll
        for (int d = 0; d < 4; ++d)
            acc[hh][d] = (f32x4){0.f, 0.f, 0.f, 0.f};

    for (int kt = 0; kt < TPC; ++kt) {
        const int k0 = chunk * (TK * TPC) + kt * TK;

        // ---- QK^T split-bf16 MFMA: s = qhi*khi + qlo*khi + qhi*klo ----
        #pragma unroll
        for (int hh = 0; hh < 2; ++hh) {
            const int h = wave * 2 + hh;
            #pragma unroll
            for (int ks = 0; ks < 2; ++ks) {
                f32x4 c = (f32x4){0.f, 0.f, 0.f, 0.f};
                #pragma unroll
                for (int kk = 0; kk < 2; ++kk) {
                    const float* kp = kg + (size_t)((b * H_ + h) * S_ + k0 + ks * 16 + n16) * D_
                                      + kk * 32 + quad * 8;
                    float4 f0 = ((const float4*)kp)[0], f1 = ((const float4*)kp)[1];
                    float fv[8] = {f0.x, f0.y, f0.z, f0.w, f1.x, f1.y, f1.z, f1.w};
                    bf16x8 khi, klo;
                    #pragma unroll
                    for (int j = 0; j < 8; ++j) {
                        __bf16 h16 = (__bf16)fv[j];
                        khi[j] = h16;
                        klo[j] = (__bf16)(fv[j] - (float)h16);
                    }
                    c = __builtin_amdgcn_mfma_f32_16x16x32_bf16(qhi[hh][kk], khi, c, 0, 0, 0);
                    c = __builtin_amdgcn_mfma_f32_16x16x32_bf16(qlo[hh][kk], khi, c, 0, 0, 0);
                    c = __builtin_amdgcn_mfma_f32_16x16x32_bf16(qhi[hh][kk], klo, c, 0, 0, 0);
                }
                #pragma unroll
                for (int r = 0; r < 4; ++r)
                    sbuf[h][quad * 4 + r][ks * 16 + n16] = c[r];
            }
        }
        __syncthreads();

        // ---- softmax ACROSS HEADS (axis=1) + mask; att -> global + LDS(bf16) ----
        #pragma unroll
        for (int rep = 0; rep < 2; ++rep) {
            const int pos = tid + rep * 256;       // 512 positions = 16q x 32k
            const int qq  = pos >> 5;
            const int kk2 = pos & 31;
            const int msk = maskg[(size_t)(b * S_ + q0 + qq) * S_ + k0 + kk2];
            float sv[8];
            float mx = -INFINITY;
            #pragma unroll
            for (int h = 0; h < H_; ++h) { sv[h] = sbuf[h][qq][kk2]; mx = fmaxf(mx, sv[h]); }
            float sum = 0.f;
            #pragma unroll
            for (int h = 0; h < H_; ++h) { sv[h] = __expf(sv[h] - mx); sum += sv[h]; }
            const float inv = 1.0f / sum;
            #pragma unroll
            for (int h = 0; h < H_; ++h) {
                const float a = (msk == 0) ? 0.125f : sv[h] * inv;  // all-masked => uniform 1/8
                attout[(size_t)((b * H_ + h) * S_ + q0 + qq) * S_ + k0 + kk2] = a;
                abuf[h][qq][kk2] = (__bf16)a;
            }
        }
        __syncthreads();

        // ---- PV: A = att from LDS, B = V^T fragments straight from global ----
        #pragma unroll
        for (int hh = 0; hh < 2; ++hh) {
            const int h = wave * 2 + hh;
            bf16x8 af = *(const bf16x8*)&abuf[h][n16][quad * 8];   // A[m=n16][k=quad*8+j]
            #pragma unroll
            for (int dsb = 0; dsb < 4; ++dsb) {
                const float* vp = vg + (size_t)((b * H_ + h) * S_ + k0 + quad * 8) * D_
                                  + dsb * 16 + n16;
                bf16x8 bf;
                #pragma unroll
                for (int j = 0; j < 8; ++j)
                    bf[j] = (__bf16)vp[(size_t)j * D_];  // B[k=quad*8+j][n=n16]
                acc[hh][dsb] = __builtin_amdgcn_mfma_f32_16x16x32_bf16(af, bf, acc[hh][dsb], 0, 0, 0);
            }
        }
        // no 3rd barrier: next iter's sbuf writes are fenced by barrier A(i+1),
        // abuf writes by the same; PV reads precede it in every wave
    }

    // ---- epilogue: accumulate this chunk's partial z via device-scope atomics ----
    #pragma unroll
    for (int hh = 0; hh < 2; ++hh) {
        const int h = wave * 2 + hh;
        #pragma unroll
        for (int dsb = 0; dsb < 4; ++dsb)
            #pragma unroll
            for (int r = 0; r < 4; ++r)
                atomicAdd(&zout[(size_t)((b * H_ + h) * S_ + q0 + quad * 4 + r) * D_
                                + dsb * 16 + n16],
                          acc[hh][dsb][r]);
    }
}

extern "C" void kernel_launch(void* const* d_in, const int* in_sizes, int n_in,
                              void* d_out, int out_size, void* d_ws, size_t ws_size,
                              hipStream_t stream) {
    const float* q    = (const float*)d_in[0];
    const float* k    = (const float*)d_in[1];
    const float* v    = (const float*)d_in[2];
    const int*   mask = (const int*)d_in[3];
    float* z   = (float*)d_out;
    float* att = (float*)d_out + (size_t)B_ * H_ * S_ * D_;   // outputs: (z, att_score)

    // z is accumulated atomically across 8 k-chunks -> must start at zero
    // (d_out is re-poisoned to 0xAA before every launch). memsetAsync is
    // graph-capture-legal on `stream`.
    hipMemsetAsync(z, 0, (size_t)B_ * H_ * S_ * D_ * sizeof(float), stream);

    attn_fused<<<dim3(KCHUNKS * B_ * (S_ / TQ)), dim3(256), 0, stream>>>(q, k, v, mask, z, att);
}

// Round 3
// 509.983 us; speedup vs baseline: 1.8359x; 1.0442x over previous
//
#include <hip/hip_runtime.h>
#include <hip/hip_bf16.h>
#include <cmath>

#define B_ 2
#define H_ 8
#define S_ 2048
#define D_ 64
#define TQ 16
#define TK 32
#define KCHUNKS 8
#define TPC ((S_ / TK) / KCHUNKS)   // 8 k-tiles of 32 per chunk

typedef __bf16 bf16x8 __attribute__((ext_vector_type(8)));
typedef float  f32x4  __attribute__((ext_vector_type(4)));

#define SB_STRIDE 42   // even (8B-aligned float2 rows), 2-way max bank aliasing
#define AB_STRIDE 40   // bf16 stride: 80B rows keep 16B-aligned A-frags

#define NK ((size_t)B_ * H_ * S_ * D_)   // 2,097,152 elements

// ---------------- prep 1: K -> bf16 hi/lo (split-bf16 for fp32-grade QK) ----------------
__global__ __launch_bounds__(256)
void prep_k(const float* __restrict__ kg, __bf16* __restrict__ khi, __bf16* __restrict__ klo)
{
    const size_t i = ((size_t)blockIdx.x * 256 + threadIdx.x) * 8;
    float4 f0 = ((const float4*)(kg + i))[0];
    float4 f1 = ((const float4*)(kg + i))[1];
    float fv[8] = {f0.x, f0.y, f0.z, f0.w, f1.x, f1.y, f1.z, f1.w};
    bf16x8 hi, lo;
    #pragma unroll
    for (int j = 0; j < 8; ++j) {
        __bf16 h = (__bf16)fv[j];
        hi[j] = h;
        lo[j] = (__bf16)(fv[j] - (float)h);
    }
    *(bf16x8*)(khi + i) = hi;
    *(bf16x8*)(klo + i) = lo;
}

// ---------------- prep 2: V -> bf16 transposed vt[b][h][d][s] ----------------
__global__ __launch_bounds__(256)
void prep_vt(const float* __restrict__ vg, __bf16* __restrict__ vt)
{
    __shared__ float tile[64][65];
    const int bh = blockIdx.x >> 5;   // 0..15 = b*H+h
    const int kt = blockIdx.x & 31;   // 64-key tile
    const int t  = threadIdx.x;
    {
        const int key = t >> 2, seg = t & 3;
        const float* src = vg + ((size_t)bh * S_ + kt * 64 + key) * D_ + seg * 16;
        #pragma unroll
        for (int i = 0; i < 4; ++i) {
            float4 f = ((const float4*)src)[i];
            tile[key][seg * 16 + i * 4 + 0] = f.x;
            tile[key][seg * 16 + i * 4 + 1] = f.y;
            tile[key][seg * 16 + i * 4 + 2] = f.z;
            tile[key][seg * 16 + i * 4 + 3] = f.w;
        }
    }
    __syncthreads();
    {
        const int d = t >> 2, seg = t & 3;
        bf16x8 o0, o1;
        #pragma unroll
        for (int j = 0; j < 8; ++j) o0[j] = (__bf16)tile[seg * 16 + j][d];
        #pragma unroll
        for (int j = 0; j < 8; ++j) o1[j] = (__bf16)tile[seg * 16 + 8 + j][d];
        __bf16* dst = vt + ((size_t)bh * D_ + d) * S_ + kt * 64 + seg * 16;
        *(bf16x8*)dst       = o0;
        *((bf16x8*)dst + 1) = o1;
    }
}

// ---------------- main fused kernel ----------------
__global__ __launch_bounds__(256, 4)
void attn_fused(const float* __restrict__ qg,
                const __bf16* __restrict__ khi_g, const __bf16* __restrict__ klo_g,
                const __bf16* __restrict__ vt_g,  const int* __restrict__ maskg,
                float* __restrict__ zout, float* __restrict__ attout)
{
    __shared__ float  sbuf[H_][TQ][SB_STRIDE];   // 21504 B
    __shared__ __bf16 abuf[H_][TQ][AB_STRIDE];   // 10240 B

    const int tid  = threadIdx.x;
    const int lane = tid & 63;
    const int wave = tid >> 6;      // wave handles heads 2w, 2w+1
    const int n16  = lane & 15;
    const int quad = lane >> 4;

    const int bi    = blockIdx.x;
    const int b     = bi & 1;
    const int qt    = (bi >> 1) & 127;
    const int chunk = bi >> 8;
    const int q0    = qt * TQ;

    const float scale = 0.35355339059327373f;  // 1/sqrt(H=8) -- k.shape[1] trap!

    // Q fragments, hi/lo split-bf16 (scaled), converted ONCE per block
    bf16x8 qhi[2][2], qlo[2][2];
    #pragma unroll
    for (int hh = 0; hh < 2; ++hh) {
        const int h = wave * 2 + hh;
        const float* qp = qg + (size_t)((b * H_ + h) * S_ + q0 + n16) * D_;
        #pragma unroll
        for (int kk = 0; kk < 2; ++kk) {
            const float4* p = (const float4*)(qp + kk * 32 + quad * 8);
            float4 f0 = p[0], f1 = p[1];
            float fv[8] = {f0.x, f0.y, f0.z, f0.w, f1.x, f1.y, f1.z, f1.w};
            bf16x8 hi, lo;
            #pragma unroll
            for (int j = 0; j < 8; ++j) {
                float fs = fv[j] * scale;
                __bf16 h16 = (__bf16)fs;
                hi[j] = h16;
                lo[j] = (__bf16)(fs - (float)h16);
            }
            qhi[hh][kk] = hi; qlo[hh][kk] = lo;
        }
    }

    f32x4 acc[2][4];
    #pragma unroll
    for (int hh = 0; hh < 2; ++hh)
        #pragma unroll
        for (int d = 0; d < 4; ++d)
            acc[hh][d] = (f32x4){0.f, 0.f, 0.f, 0.f};

    // softmax-phase thread mapping: qq row + pair of k columns
    const int sqq = tid >> 4;
    const int skp = (tid & 15) * 2;

    for (int kt = 0; kt < TPC; ++kt) {
        const int k0 = chunk * (TK * TPC) + kt * TK;

        // ---- QK^T: pre-converted bf16 hi/lo K frags, 3-term split-bf16 MFMA ----
        #pragma unroll
        for (int hh = 0; hh < 2; ++hh) {
            const int h = wave * 2 + hh;
            #pragma unroll
            for (int ks = 0; ks < 2; ++ks) {
                const size_t krow = ((size_t)(b * H_ + h) * S_ + k0 + ks * 16 + n16) * D_
                                    + quad * 8;
                f32x4 c = (f32x4){0.f, 0.f, 0.f, 0.f};
                #pragma unroll
                for (int kk = 0; kk < 2; ++kk) {
                    bf16x8 khi = *(const bf16x8*)(khi_g + krow + kk * 32);
                    bf16x8 klo = *(const bf16x8*)(klo_g + krow + kk * 32);
                    c = __builtin_amdgcn_mfma_f32_16x16x32_bf16(qhi[hh][kk], khi, c, 0, 0, 0);
                    c = __builtin_amdgcn_mfma_f32_16x16x32_bf16(qlo[hh][kk], khi, c, 0, 0, 0);
                    c = __builtin_amdgcn_mfma_f32_16x16x32_bf16(qhi[hh][kk], klo, c, 0, 0, 0);
                }
                #pragma unroll
                for (int r = 0; r < 4; ++r)
                    sbuf[h][quad * 4 + r][ks * 16 + n16] = c[r];
            }
        }
        __syncthreads();

        // ---- softmax ACROSS HEADS (axis=1) + mask; att -> global(float2) + LDS ----
        {
            const int2 m2 = *(const int2*)&maskg[(size_t)(b * S_ + q0 + sqq) * S_ + k0 + skp];
            float2 sv[8];
            float mx0 = -INFINITY, mx1 = -INFINITY;
            #pragma unroll
            for (int h = 0; h < H_; ++h) {
                float2 s = *(const float2*)&sbuf[h][sqq][skp];
                sv[h] = s;
                mx0 = fmaxf(mx0, s.x); mx1 = fmaxf(mx1, s.y);
            }
            float sum0 = 0.f, sum1 = 0.f;
            #pragma unroll
            for (int h = 0; h < H_; ++h) {
                sv[h].x = __expf(sv[h].x - mx0); sum0 += sv[h].x;
                sv[h].y = __expf(sv[h].y - mx1); sum1 += sv[h].y;
            }
            const float inv0 = 1.0f / sum0, inv1 = 1.0f / sum1;
            #pragma unroll
            for (int h = 0; h < H_; ++h) {
                // all-heads-masked => ties => uniform softmax = 1/8
                const float a0 = (m2.x == 0) ? 0.125f : sv[h].x * inv0;
                const float a1 = (m2.y == 0) ? 0.125f : sv[h].y * inv1;
                *(float2*)&attout[(size_t)((b * H_ + h) * S_ + q0 + sqq) * S_ + k0 + skp]
                    = make_float2(a0, a1);
                union { __bf16 bh2[2]; unsigned u; } pk;
                pk.bh2[0] = (__bf16)a0; pk.bh2[1] = (__bf16)a1;
                *(unsigned*)&abuf[h][sqq][skp] = pk.u;
            }
        }
        __syncthreads();

        // ---- PV: A = att from LDS, B = pre-transposed bf16 V^T (16B loads) ----
        #pragma unroll
        for (int hh = 0; hh < 2; ++hh) {
            const int h = wave * 2 + hh;
            bf16x8 af = *(const bf16x8*)&abuf[h][n16][quad * 8];   // A[m=n16][k=quad*8+j]
            #pragma unroll
            for (int dsb = 0; dsb < 4; ++dsb) {
                bf16x8 bf = *(const bf16x8*)(vt_g
                    + ((size_t)(b * H_ + h) * D_ + dsb * 16 + n16) * S_ + k0 + quad * 8);
                acc[hh][dsb] = __builtin_amdgcn_mfma_f32_16x16x32_bf16(af, bf, acc[hh][dsb], 0, 0, 0);
            }
        }
        // no 3rd barrier: next-iter sbuf/abuf writes are fenced by the next barriers
    }

    // ---- epilogue: accumulate partial z across k-chunks via device atomics ----
    #pragma unroll
    for (int hh = 0; hh < 2; ++hh) {
        const int h = wave * 2 + hh;
        #pragma unroll
        for (int dsb = 0; dsb < 4; ++dsb)
            #pragma unroll
            for (int r = 0; r < 4; ++r)
                atomicAdd(&zout[(size_t)((b * H_ + h) * S_ + q0 + quad * 4 + r) * D_
                                + dsb * 16 + n16],
                          acc[hh][dsb][r]);
    }
}

extern "C" void kernel_launch(void* const* d_in, const int* in_sizes, int n_in,
                              void* d_out, int out_size, void* d_ws, size_t ws_size,
                              hipStream_t stream) {
    const float* q    = (const float*)d_in[0];
    const float* k    = (const float*)d_in[1];
    const float* v    = (const float*)d_in[2];
    const int*   mask = (const int*)d_in[3];
    float* z   = (float*)d_out;
    float* att = (float*)d_out + NK;   // outputs: (z, att_score)

    // workspace layout: khi | klo | vt   (bf16 each, NK elements) = 12.6 MB
    __bf16* khi = (__bf16*)d_ws;
    __bf16* klo = khi + NK;
    __bf16* vt  = klo + NK;

    prep_k <<<dim3(NK / (256 * 8)), dim3(256), 0, stream>>>(k, khi, klo);
    prep_vt<<<dim3(B_ * H_ * (S_ / 64)), dim3(256), 0, stream>>>(v, vt);

    // z accumulated atomically across 8 k-chunks -> must start at zero
    hipMemsetAsync(z, 0, NK * sizeof(float), stream);

    attn_fused<<<dim3(KCHUNKS * B_ * (S_ / TQ)), dim3(256), 0, stream>>>(
        q, khi, klo, vt, mask, z, att);
}